// Round 13
// baseline (501.266 us; speedup 1.0000x reference)
//
#include <hip/hip_runtime.h>
#include <hip/hip_bf16.h>
#include <float.h>
#include <math.h>

// ---------------------------------------------------------------------------
// B=8, NCH=4, NPTS=1024, NGT=10, NANCH=5120, M=128, NPOOL=64, EXT=0.2
// NEW_CENTERS: (0,0,1),(0,0,-1),(2.5,0,-1),(2.5,0,1),(2.5,0,0)
// ---------------------------------------------------------------------------

typedef __attribute__((ext_vector_type(8))) short short8;
typedef __attribute__((ext_vector_type(4))) float f32x4;

#define FMA16()                                                                 \
  do {                                                                          \
    float4 av = *(const float4*)&sWT[cc][to * 4];                               \
    float4 bv = *(const float4*)&sB[cc][tk * 4];                                \
    acc[0][0] = fmaf(av.x, bv.x, acc[0][0]);                                    \
    acc[0][1] = fmaf(av.x, bv.y, acc[0][1]);                                    \
    acc[0][2] = fmaf(av.x, bv.z, acc[0][2]);                                    \
    acc[0][3] = fmaf(av.x, bv.w, acc[0][3]);                                    \
    acc[1][0] = fmaf(av.y, bv.x, acc[1][0]);                                    \
    acc[1][1] = fmaf(av.y, bv.y, acc[1][1]);                                    \
    acc[1][2] = fmaf(av.y, bv.z, acc[1][2]);                                    \
    acc[1][3] = fmaf(av.y, bv.w, acc[1][3]);                                    \
    acc[2][0] = fmaf(av.z, bv.x, acc[2][0]);                                    \
    acc[2][1] = fmaf(av.z, bv.y, acc[2][1]);                                    \
    acc[2][2] = fmaf(av.z, bv.z, acc[2][2]);                                    \
    acc[2][3] = fmaf(av.z, bv.w, acc[2][3]);                                    \
    acc[3][0] = fmaf(av.w, bv.x, acc[3][0]);                                    \
    acc[3][1] = fmaf(av.w, bv.y, acc[3][1]);                                    \
    acc[3][2] = fmaf(av.w, bv.z, acc[3][2]);                                    \
    acc[3][3] = fmaf(av.w, bv.w, acc[3][3]);                                    \
  } while (0)

// ---------------- init: copy gt tail + zero rank array ----------------------
__global__ void init_kernel(const float* __restrict__ gt, float* __restrict__ o_gt,
                            int* __restrict__ rank) {
  int t = blockIdx.x * 256 + threadIdx.x;
  if (t < 40960) rank[t] = 0;
  if (t < 90) o_gt[t] = gt[630 + t];
}

// ---------------- pointnet 1x1 conv (+optional input affine/relu) -----------
template <int C, int O, bool AFF, bool RELU, bool TRANS>
__global__ __launch_bounds__(256) void conv_pn(const float* __restrict__ in,
                                               const float* __restrict__ w,
                                               const float* __restrict__ bias,
                                               const float* __restrict__ aff,
                                               float* __restrict__ out) {
  __shared__ __align__(16) float sB[64][68];
  __shared__ __align__(16) float sWT[64][68];
  const int i0 = blockIdx.x * 64;
  const int o0 = blockIdx.y * 64;
  const int b = blockIdx.z;
  const int tid = threadIdx.x;
  const int tk = tid & 15, to = tid >> 4;
  float acc[4][4] = {};
  for (int c0 = 0; c0 < C; c0 += 64) {
    const int cs = (C - c0 < 64) ? (C - c0) : 64;
    for (int idx = tid; idx < 4096; idx += 256) {
      int ii = idx & 63, cc = idx >> 6;
      float v = 0.f;
      if (cc < cs) {
        int c = c0 + cc;
        v = in[(b * C + c) * 1024 + i0 + ii];
        if (AFF) v = fmaf(v, aff[c], aff[C + c]);
        if (RELU) v = fmaxf(v, 0.f);
      }
      sB[cc][ii] = v;
    }
    for (int idx = tid; idx < 4096; idx += 256) {
      int cc = idx & 63, oo = idx >> 6;
      sWT[cc][oo] = (cc < cs) ? w[(o0 + oo) * C + c0 + cc] : 0.f;
    }
    __syncthreads();
    for (int cc = 0; cc < cs; ++cc) { FMA16(); }
    __syncthreads();
  }
  if (TRANS) {
    float b0 = bias[o0 + to * 4], b1 = bias[o0 + to * 4 + 1];
    float b2 = bias[o0 + to * 4 + 2], b3 = bias[o0 + to * 4 + 3];
#pragma unroll
    for (int jj = 0; jj < 4; ++jj) {
      float4 v = make_float4(acc[0][jj] + b0, acc[1][jj] + b1, acc[2][jj] + b2, acc[3][jj] + b3);
      *(float4*)&out[((size_t)(b * 1024) + i0 + tk * 4 + jj) * O + o0 + to * 4] = v;
    }
  } else {
    for (int j = 0; j < 4; ++j) {
      int o = o0 + to * 4 + j;
      float bs = bias[o];
      float4 v = make_float4(acc[j][0] + bs, acc[j][1] + bs, acc[j][2] + bs, acc[j][3] + bs);
      *(float4*)&out[(b * O + o) * 1024 + i0 + tk * 4] = v;
    }
  }
}

// ---------------- BN stats over (B=8, N=1024) per channel -> affine ---------
__global__ __launch_bounds__(256) void bn_stats(const float* __restrict__ x,
                                                const float* __restrict__ g,
                                                const float* __restrict__ be,
                                                float* __restrict__ aff, int C) {
#pragma clang fp contract(off)
  int c = blockIdx.x;
  int tid = threadIdx.x;
  float s = 0.f, q = 0.f;
  for (int idx = tid; idx < 8192; idx += 256) {
    int b = idx >> 10, i = idx & 1023;
    float v = x[(b * C + c) * 1024 + i];
    s += v;
    q += v * v;
  }
  for (int m = 1; m < 64; m <<= 1) {
    s += __shfl_xor(s, m);
    q += __shfl_xor(q, m);
  }
  __shared__ float as_[4], aq_[4];
  int wv = tid >> 6;
  if ((tid & 63) == 0) { as_[wv] = s; aq_[wv] = q; }
  __syncthreads();
  if (tid == 0) {
    s = as_[0] + as_[1] + as_[2] + as_[3];
    q = aq_[0] + aq_[1] + aq_[2] + aq_[3];
    float m_ = s * (1.f / 8192.f);
    float var = q * (1.f / 8192.f) - m_ * m_;
    float A = g[c] / sqrtf(var + 1e-5f);
    aff[c] = A;
    aff[C + c] = be[c] - m_ * A;
  }
}

// ---------------- BN stats for transposed layout [8192][256] ----------------
__global__ __launch_bounds__(256) void bn_stats_t(const float* __restrict__ x,
                                                  const float* __restrict__ g,
                                                  const float* __restrict__ be,
                                                  float* __restrict__ aff) {
#pragma clang fp contract(off)
  int c = blockIdx.x;
  int tid = threadIdx.x;
  float s = 0.f, q = 0.f;
  for (int idx = tid; idx < 8192; idx += 256) {
    float v = x[(size_t)idx * 256 + c];
    s += v;
    q += v * v;
  }
  for (int m = 1; m < 64; m <<= 1) {
    s += __shfl_xor(s, m);
    q += __shfl_xor(q, m);
  }
  __shared__ float as_[4], aq_[4];
  int wv = tid >> 6;
  if ((tid & 63) == 0) { as_[wv] = s; aq_[wv] = q; }
  __syncthreads();
  if (tid == 0) {
    s = as_[0] + as_[1] + as_[2] + as_[3];
    q = aq_[0] + aq_[1] + aq_[2] + aq_[3];
    float m_ = s * (1.f / 8192.f);
    float var = q * (1.f / 8192.f) - m_ * m_;
    float A = g[c] / sqrtf(var + 1e-5f);
    aff[c] = A;
    aff[256 + c] = be[c] - m_ * A;
  }
}

// ---------------- BEV IoU (no fp contraction: match XLA elementwise) --------
__device__ float bev_iou_ga(const float* gx, const float* gz, float garea, float ax, float az) {
#pragma clang fp contract(off)
  float px[8], pz[8], ox[8], oz[8];
#pragma unroll
  for (int i = 0; i < 4; ++i) {
    px[i] = gx[i];
    pz[i] = gz[i];
    px[i + 4] = 0.f;
    pz[i + 4] = 0.f;
  }
  int count = 4;
  float kx[4], kz[4];
  kx[0] = ax + 1.f;  kz[0] = az + 2.5f;
  kx[1] = ax - 1.f;  kz[1] = az + 2.5f;
  kx[2] = ax - 1.f;  kz[2] = az - 2.5f;
  kx[3] = ax + 1.f;  kz[3] = az - 2.5f;
#pragma unroll
  for (int e = 0; e < 4; ++e) {
    float e1x = kx[e], e1z = kz[e];
    float e2x = kx[(e + 1) & 3], e2z = kz[(e + 1) & 3];
    float ex = e2x - e1x, ez = e2z - e1z;
    int cnt = count > 1 ? count : 1;
    int lim = count < 8 ? count : 8;
    int p = 0;
    for (int idx = 0; idx < lim; ++idx) {
      int ni = (idx + 1) % cnt;
      if (ni > 7) ni = 7;
      float cx = px[idx], cz = pz[idx];
      float nx = px[ni], nz = pz[ni];
      float dc = ex * (cz - e1z) - ez * (cx - e1x);
      float dn = ex * (nz - e1z) - ez * (nx - e1x);
      bool ic = dc >= 0.f, in_ = dn >= 0.f;
      if (ic) {
        if (p < 8) { ox[p] = cx; oz[p] = cz; }
        ++p;
      }
      if (ic != in_) {
        float den = dc - dn;
        float t = dc / (fabsf(den) < 1e-9f ? 1e-9f : den);
        if (p < 8) { ox[p] = cx + t * (nx - cx); oz[p] = cz + t * (nz - cz); }
        ++p;
      }
    }
    count = p;
    int cp = p < 8 ? p : 8;
#pragma unroll
    for (int i = 0; i < 8; ++i) {
      px[i] = (i < cp) ? ox[i] : 0.f;
      pz[i] = (i < cp) ? oz[i] : 0.f;
    }
  }
  int cnt = count > 1 ? count : 1;
  int lim = count < 8 ? count : 8;
  float ssum = 0.f;
  for (int idx = 0; idx < lim; ++idx) {
    int ni = (idx + 1) % cnt;
    if (ni > 7) ni = 7;
    ssum += px[idx] * pz[ni] - px[ni] * pz[idx];
  }
  float inter = 0.5f * fabsf(ssum);
  return inter / fmaxf(garea + 10.f - inter, 1e-8f);
}

// ---------------- iou: one (anchor, gt) per thread, grid (20,8,10) ----------
__global__ __launch_bounds__(256) void iou_kernel(const float* __restrict__ points,
                                                  const float* __restrict__ gt,
                                                  float* __restrict__ iou10) {
#pragma clang fp contract(off)
  int b = blockIdx.y, g = blockIdx.z;
  int a = blockIdx.x * 256 + threadIdx.x;
  const float* L = gt + b * 90 + g * 9;
  float gxx = L[3], gzz = L[5], gw = L[0], gl = L[2], gth = L[6];
  float c = cosf(gth), s = sinf(gth);
  const float sx[4] = {0.5f, -0.5f, -0.5f, 0.5f};
  const float sz[4] = {0.5f, 0.5f, -0.5f, -0.5f};
  float gcx[4], gcz[4];
#pragma unroll
  for (int k = 0; k < 4; ++k) {
    float lx = sx[k] * gw, lz = sz[k] * gl;
    gcx[k] = gxx + lx * c - lz * s;
    gcz[k] = gzz + lx * s + lz * c;
  }
  float garea = gw * gl;
  int pt = a / 5, j = a % 5;
  const float CX[5] = {0.f, 0.f, 2.5f, 2.5f, 2.5f};
  const float CZ[5] = {1.f, -1.f, -1.f, 1.f, 0.f};
  const float* P = points + b * 4096;
  float ax = P[pt] - CX[j];
  float az = P[2048 + pt] - CZ[j];
  iou10[(size_t)(b * 10 + g) * 5120 + a] = bev_iou_ga(gcx, gcz, garea, ax, az);
}

// ---------------- argmax over g (strict >, first max wins) ------------------
__global__ __launch_bounds__(256) void iou_reduce(const float* __restrict__ iou10,
                                                  float* __restrict__ maxiou,
                                                  int* __restrict__ maxind) {
  int b = blockIdx.y;
  int a = blockIdx.x * 256 + threadIdx.x;
  float best = -1.f;
  int bi = 0;
  for (int g = 0; g < 10; ++g) {
    float v = iou10[(size_t)(b * 10 + g) * 5120 + a];
    if (v > best) { best = v; bi = g; }
  }
  maxiou[b * 5120 + a] = best;
  maxind[b * 5120 + a] = bi;
}

// ---------------- rank: partial counts over j-chunks (order-independent) ----
__global__ __launch_bounds__(256) void select_rank(const float* __restrict__ maxiou,
                                                   int* __restrict__ rank) {
  __shared__ __align__(16) float vals[640];
  int b = blockIdx.y, chunk = blockIdx.z, tid = threadIdx.x;
  int jb0 = chunk * 640;
  for (int i = tid; i < 640; i += 256) vals[i] = maxiou[b * 5120 + jb0 + i];
  int a = blockIdx.x * 256 + tid;
  float av = maxiou[b * 5120 + a];
  __syncthreads();
  int rk = 0;
#pragma unroll 4
  for (int j4 = 0; j4 < 160; ++j4) {
    float4 v = *(const float4*)&vals[j4 * 4];
    int jb = jb0 + j4 * 4;
    rk += (v.x < av) || (v.x == av && jb < a);
    rk += (v.y < av) || (v.y == av && jb + 1 < a);
    rk += (v.z < av) || (v.z == av && jb + 2 < a);
    rk += (v.w < av) || (v.w == av && jb + 3 < a);
  }
  atomicAdd(&rank[b * 5120 + a], rk);
}

// ---------------- write selected rows from final ranks ----------------------
__global__ __launch_bounds__(256) void select_write(const int* __restrict__ rank,
                                                    const float* __restrict__ maxiou,
                                                    const int* __restrict__ maxind,
                                                    const float* __restrict__ points,
                                                    float* __restrict__ o_lbl,
                                                    float* __restrict__ o_iou,
                                                    float* __restrict__ o_box,
                                                    float* __restrict__ o_idx) {
#pragma clang fp contract(off)
  int b = blockIdx.y, tid = threadIdx.x;
  int a = blockIdx.x * 256 + tid;
  int rk = rank[b * 5120 + a];
  int slot = -1;
  if (rk < 64) slot = rk;
  else if (rk >= 5056) slot = rk - 4992;  // 64 + (rk - 5056)
  if (slot >= 0) {
    const float CX[5] = {0.f, 0.f, 2.5f, 2.5f, 2.5f};
    const float CZ[5] = {1.f, -1.f, -1.f, 1.f, 0.f};
    int base = b * 128 + slot;
    float av = maxiou[b * 5120 + a];
    o_iou[base] = av;
    o_lbl[base] = av > 0.5f ? 1.f : 0.f;
    o_idx[base] = (float)maxind[b * 5120 + a];
    int pt = a / 5, j = a % 5;
    const float* P = points + b * 4096;
    float* bx = o_box + base * 7;
    bx[0] = P[pt] - CX[j];
    bx[1] = P[1024 + pt];
    bx[2] = P[2048 + pt] - CZ[j];
    bx[3] = 2.f;
    bx[4] = 2.f;
    bx[5] = 5.f;
    bx[6] = 0.f;
  }
}

// ---------------- pooling: ballot-based, exact point-index order ------------
__global__ __launch_bounds__(256) void pool_kernel(const float* __restrict__ points,
                                                   const float* __restrict__ selboxes,
                                                   int* __restrict__ selpts) {
#pragma clang fp contract(off)
  int box = blockIdx.x * 4 + (threadIdx.x >> 6);
  int lane = threadIdx.x & 63;
  int b = box >> 7;
  const float* bx = selboxes + box * 7;
  float b0 = bx[0], b1 = bx[1], b2 = bx[2], b3 = bx[3], b4 = bx[4], b5 = bx[5];
  float limx = b4 * 0.5f + 0.2f, limz = b5 * 0.5f + 0.2f;
  float ylo = b1 - b3 - 0.2f, yhi = b1 + 0.2f;
  const float* P = points + b * 4096;
  unsigned long long m[16];
  int total_in = 0;
#pragma unroll
  for (int r = 0; r < 16; ++r) {
    int pt = r * 64 + lane;
    float dx = P[pt] - b0;
    float py = P[1024 + pt];
    float dz = P[2048 + pt] - b2;
    bool ins = (fabsf(dx) < limx) && (fabsf(dz) < limz) && (py > ylo) && (py < yhi);
    m[r] = __ballot(ins);
    total_in += __popcll(m[r]);
  }
  unsigned long long lowmask = (1ull << lane) - 1;
  int cum = 0;
#pragma unroll
  for (int r = 0; r < 16; ++r) {
    int pt = r * 64 + lane;
    int inbefore = cum + __popcll(m[r] & lowmask);
    bool ins = (m[r] >> lane) & 1;
    int slot = ins ? inbefore : total_in + (pt - inbefore);
    if (slot < 64) selpts[box * 64 + slot] = pt | (ins ? 0x10000 : 0);
    cum += __popcll(m[r]);
  }
}

// ---------------- gather pooled features -> bf16 B-fragment order -----------
__global__ __launch_bounds__(256) void gather_pf(const float* __restrict__ out3T,
                                                 const float* __restrict__ points,
                                                 const int* __restrict__ selpts,
                                                 const float* __restrict__ selboxes,
                                                 const float* __restrict__ aff3,
                                                 unsigned short* __restrict__ pff) {
  __shared__ int sSel[64];
  __shared__ float sCen[3];
  __shared__ float sA3[256], sB3[256];
  const int bm = blockIdx.x;
  const int b = bm >> 7;
  const int tid = threadIdx.x;
  if (tid < 64) sSel[tid] = selpts[bm * 64 + tid];
  if (tid >= 64 && tid < 67) sCen[tid - 64] = selboxes[bm * 7 + (tid - 64)];
  sA3[tid] = aff3[tid];
  sB3[tid] = aff3[256 + tid];
  __syncthreads();
  const int pool = tid >> 2, part = tid & 3;
  const int ni = pool >> 4, nib = pool & 15;
  const int sv = sSel[pool];
  const int pt = sv & 0xFFFF;
  const bool valid = (sv >> 16) != 0;
  const float* row = out3T + ((size_t)(b << 10) + pt) * 256;
#pragma unroll
  for (int ks = 0; ks < 8; ++ks) {
    int c0 = ks * 32 + part * 8;
    float4 x0 = *(const float4*)&row[c0];
    float4 x1 = *(const float4*)&row[c0 + 4];
    float v[8] = {x0.x, x0.y, x0.z, x0.w, x1.x, x1.y, x1.z, x1.w};
    union { __hip_bfloat16 h[8]; uint4 u; } pk;
#pragma unroll
    for (int e = 0; e < 8; ++e) {
      float vv = valid ? fmaf(v[e], sA3[c0 + e], sB3[c0 + e]) : 0.f;
      pk.h[e] = __float2bfloat16(vv);
    }
    *(uint4*)&pff[((size_t)((bm * 9 + ks) * 4 + ni) * 64 + part * 16 + nib) * 8] = pk.u;
  }
  union { __hip_bfloat16 h[8]; uint4 u; } pk;
#pragma unroll
  for (int e = 0; e < 8; ++e) pk.h[e] = __float2bfloat16(0.f);
  if (part == 0) {
#pragma unroll
    for (int d = 0; d < 3; ++d) {
      float pv = valid ? points[(b * 4 + d) * 1024 + pt] : 0.f;
      pk.h[d] = __float2bfloat16(pv - sCen[d]);
    }
  }
  *(uint4*)&pff[((size_t)((bm * 9 + 8) * 4 + ni) * 64 + part * 16 + nib) * 8] = pk.u;
}

// ---------------- prep W1: A-fragment order [tile32][ks9][lane64][8] --------
__global__ __launch_bounds__(64) void prep_w1(const float* __restrict__ w1,
                                              unsigned short* __restrict__ W1f) {
  int o = blockIdx.x;
  int lp = threadIdx.x;
  if (lp >= 36) return;
  int ks = lp >> 2, quad = lp & 3;
  int tile = o >> 4;
  union { __hip_bfloat16 h[8]; uint4 u; } pk;
#pragma unroll
  for (int j = 0; j < 8; ++j) {
    int c = ks * 32 + quad * 8 + j;
    float v = (c < 259) ? w1[o * 259 + c] : 0.f;
    pk.h[j] = __float2bfloat16(v);
  }
  *(uint4*)&W1f[((size_t)(tile * 9 + ks) * 64 + quad * 16 + (o & 15)) * 8] = pk.u;
}

// ---------------- rp1: LDS-free register MFMA + ot-fastest XCD swizzle ------
__global__ __launch_bounds__(256) void rp1_mfma(const unsigned short* __restrict__ W1f,
                                                const unsigned short* __restrict__ pff,
                                                const float* __restrict__ bias1,
                                                unsigned short* __restrict__ g1x,
                                                float* __restrict__ psum4,
                                                float* __restrict__ psq4) {
  const int tid = threadIdx.x;
  const int lane = tid & 63, w = tid >> 6;
  const int quad = lane >> 4, nib = lane & 15;
  const int l = blockIdx.x;            // 2048 blocks
  const int xcd = l & 7;
  const int j = l >> 3;                // 0..255
  const int ot = j & 1;
  const int bm = xcd * 128 + (j >> 1);
  const unsigned short* Aw = &W1f[((size_t)(ot * 4 + w) * 4 * 9 * 64 + lane) * 8];
  const unsigned short* Bw = &pff[((size_t)(bm * 9) * 4 * 64 + lane) * 8];
  f32x4 acc[4][4] = {};
#pragma unroll
  for (int ks = 0; ks < 9; ++ks) {
    short8 af[4], bf[4];
#pragma unroll
    for (int mi = 0; mi < 4; ++mi)
      af[mi] = *(const short8*)&Aw[(size_t)(mi * 9 + ks) * 512];
#pragma unroll
    for (int ni = 0; ni < 4; ++ni)
      bf[ni] = *(const short8*)&Bw[(size_t)(ks * 4 + ni) * 512];
#pragma unroll
    for (int mi = 0; mi < 4; ++mi)
#pragma unroll
      for (int ni = 0; ni < 4; ++ni)
        acc[mi][ni] = __builtin_amdgcn_mfma_f32_16x16x32_bf16(af[mi], bf[ni], acc[mi][ni], 0, 0, 0);
  }
  const int cbase = ot * 256 + w * 64;
#pragma unroll
  for (int mi = 0; mi < 4; ++mi) {
    float bv[4];
#pragma unroll
    for (int r = 0; r < 4; ++r) bv[r] = bias1[cbase + mi * 16 + quad * 4 + r];
    float s[4] = {0.f, 0.f, 0.f, 0.f}, q[4] = {0.f, 0.f, 0.f, 0.f};
    const int kgbase = (cbase + mi * 16) >> 3;
#pragma unroll
    for (int ni = 0; ni < 4; ++ni) {
      union { __hip_bfloat16 h[4]; unsigned int u[2]; } pk;
#pragma unroll
      for (int r = 0; r < 4; ++r) {
        float v = acc[mi][ni][r] + bv[r];
        pk.h[r] = __float2bfloat16(v);
        s[r] += v;
        q[r] += v * v;
      }
      unsigned int p0 = (unsigned int)__shfl_xor((int)pk.u[0], 16);
      unsigned int p1 = (unsigned int)__shfl_xor((int)pk.u[1], 16);
      if ((quad & 1) == 0) {
        uint4 g = make_uint4(pk.u[0], pk.u[1], p0, p1);
        int kg = kgbase + (quad >> 1);
        *(uint4*)&g1x[((size_t)(bm * 64 + kg) * 64 + ni * 16 + nib) * 8] = g;
      }
    }
#pragma unroll
    for (int r = 0; r < 4; ++r) {
      float ss = s[r], qq = q[r];
#pragma unroll
      for (int msk = 1; msk < 16; msk <<= 1) {
        ss += __shfl_xor(ss, msk);
        qq += __shfl_xor(qq, msk);
      }
      if (nib == 0) {
        int o = cbase + mi * 16 + quad * 4 + r;
        psum4[bm * 512 + o] = ss;
        psq4[bm * 512 + o] = qq;
      }
    }
  }
}

// ---------------- BN affine from per-bm partials (C=512 or 1024) -----------
__global__ __launch_bounds__(64) void bn_aff_part(const float* __restrict__ psum,
                                                  const float* __restrict__ psq,
                                                  const float* __restrict__ g,
                                                  const float* __restrict__ be,
                                                  float* __restrict__ aff, int C) {
#pragma clang fp contract(off)
  int o = blockIdx.x;
  int lane = threadIdx.x;
  float s = 0.f, q = 0.f;
  for (int i = 0; i < 16; ++i) {
    int bm = i * 64 + lane;
    s += psum[(size_t)bm * C + o];
    q += psq[(size_t)bm * C + o];
  }
  for (int m = 1; m < 64; m <<= 1) {
    s += __shfl_xor(s, m);
    q += __shfl_xor(q, m);
  }
  if (lane == 0) {
    float m_ = s * (1.f / 65536.f);
    float var = q * (1.f / 65536.f) - m_ * m_;
    float A = g[o] / sqrtf(var + 1e-5f);
    aff[o] = A;
    aff[C + o] = be[o] - m_ * A;
  }
}

// ---------------- prep W2: fold BN4, A-fragment order [tile64][ks16][lane][8]
__global__ __launch_bounds__(64) void prep_w2(const float* __restrict__ w2,
                                              const float* __restrict__ b2,
                                              const float* __restrict__ aff4,
                                              unsigned short* __restrict__ W2f,
                                              float* __restrict__ bias2p) {
  int o = blockIdx.x;
  int lp = threadIdx.x;
  int ks = lp >> 2, quad = lp & 3;
  int tile = o >> 4;
  float accb = 0.f;
  union { __hip_bfloat16 h[8]; uint4 u; } pk;
#pragma unroll
  for (int j = 0; j < 8; ++j) {
    int c = ks * 32 + quad * 8 + j;
    float wv = w2[o * 512 + c];
    pk.h[j] = __float2bfloat16(wv * aff4[c]);
    accb += wv * aff4[512 + c];
  }
  *(uint4*)&W2f[((size_t)(tile * 16 + ks) * 64 + quad * 16 + (o & 15)) * 8] = pk.u;
  for (int m = 1; m < 64; m <<= 1) accb += __shfl_xor(accb, m);
  if (lp == 0) bias2p[o] = b2[o] + accb;
}

// ---------------- rp2: 2 bm per block — A fragment amortized over 2 B tiles -
// A traffic (W2f through per-XCD L2) was the binding constraint: every bm
// needs the whole 1 MB W2f. Processing 2 bm per block halves total A bytes
// and doubles MFMA per A-load (4 A-loads -> 32 MFMA).
__global__ __launch_bounds__(256) void rp2_mfma(const unsigned short* __restrict__ W2f,
                                                const unsigned short* __restrict__ g1x,
                                                const float* __restrict__ bias2p,
                                                float* __restrict__ maxb,
                                                float* __restrict__ minb,
                                                float* __restrict__ psum,
                                                float* __restrict__ psq) {
  __shared__ __align__(16) unsigned short sBl[2][8192];  // 32 KB
  const int tid = threadIdx.x;
  const int lane = tid & 63, w = tid >> 6;
  const int quad = lane >> 4, nib = lane & 15;
  const int l = blockIdx.x;            // 2048 blocks
  const int xcd = l & 7;
  const int j = l >> 3;                // 0..255
  const int ot = j & 3;
  const int bm0 = (xcd * 64 + (j >> 2)) * 2;
  const unsigned short* Aw = &W2f[((size_t)(ot * 4 + w) * 4 * 16 * 64 + lane) * 8];
  const uint4* gB0 = (const uint4*)&g1x[(size_t)bm0 * 32768];
  const uint4* gB1 = (const uint4*)&g1x[((size_t)bm0 + 1) * 32768];
  f32x4 acc[2][4][4] = {};
#pragma unroll
  for (int c = 0; c < 4; ++c) {
#pragma unroll
    for (int it = 0; it < 4; ++it) {
      *(uint4*)&sBl[0][(it * 256 + tid) * 8] = gB0[c * 1024 + it * 256 + tid];
      *(uint4*)&sBl[1][(it * 256 + tid) * 8] = gB1[c * 1024 + it * 256 + tid];
    }
    __syncthreads();
#pragma unroll
    for (int kl = 0; kl < 4; ++kl) {
      const int ks = c * 4 + kl;
      short8 af[4];
#pragma unroll
      for (int mi = 0; mi < 4; ++mi)
        af[mi] = *(const short8*)&Aw[(size_t)(mi * 16 + ks) * 512];
#pragma unroll
      for (int p = 0; p < 2; ++p) {
        short8 bf[4];
#pragma unroll
        for (int ni = 0; ni < 4; ++ni)
          bf[ni] = *(const short8*)&sBl[p][((kl * 4 + quad) * 64 + ni * 16 + nib) * 8];
#pragma unroll
        for (int mi = 0; mi < 4; ++mi)
#pragma unroll
          for (int ni = 0; ni < 4; ++ni)
            acc[p][mi][ni] =
                __builtin_amdgcn_mfma_f32_16x16x32_bf16(af[mi], bf[ni], acc[p][mi][ni], 0, 0, 0);
      }
    }
    __syncthreads();
  }
  const int obase = ot * 256 + w * 64;
#pragma unroll
  for (int p = 0; p < 2; ++p) {
    const int bm = bm0 + p;
#pragma unroll
    for (int mi = 0; mi < 4; ++mi) {
#pragma unroll
      for (int r = 0; r < 4; ++r) {
        int o = obase + mi * 16 + quad * 4 + r;
        float bs = bias2p[o];
        float v0 = acc[p][mi][0][r] + bs;
        float v1 = acc[p][mi][1][r] + bs;
        float v2 = acc[p][mi][2][r] + bs;
        float v3 = acc[p][mi][3][r] + bs;
        float mx = fmaxf(fmaxf(v0, v1), fmaxf(v2, v3));
        float mn = fminf(fminf(v0, v1), fminf(v2, v3));
        float s = v0 + v1 + v2 + v3;
        float q = v0 * v0 + v1 * v1 + v2 * v2 + v3 * v3;
#pragma unroll
        for (int msk = 1; msk < 16; msk <<= 1) {
          mx = fmaxf(mx, __shfl_xor(mx, msk));
          mn = fminf(mn, __shfl_xor(mn, msk));
          s += __shfl_xor(s, msk);
          q += __shfl_xor(q, msk);
        }
        if (nib == 0) {
          maxb[bm * 1024 + o] = mx;
          minb[bm * 1024 + o] = mn;
          psum[bm * 1024 + o] = s;
          psq[bm * 1024 + o] = q;
        }
      }
    }
  }
}

// ---------------- feats: monotone-affine max over NPOOL --------------------
__global__ void feats_kernel(const float* __restrict__ maxb, const float* __restrict__ minb,
                             const float* __restrict__ aff5, float* __restrict__ o_feats) {
#pragma clang fp contract(off)
  int i = blockIdx.x * 256 + threadIdx.x;
  int o = i & 1023;
  float A = aff5[o], Bv = aff5[1024 + o];
  float v = (A >= 0.f) ? maxb[i] : minb[i];
  o_feats[i] = v * A + Bv;
}

// ---------------------------------------------------------------------------
extern "C" void kernel_launch(void* const* d_in, const int* in_sizes, int n_in,
                              void* d_out, int out_size, void* d_ws, size_t ws_size,
                              hipStream_t stream) {
  (void)in_sizes; (void)n_in; (void)out_size; (void)ws_size;
  const float* points = (const float*)d_in[0];
  const float* gt = (const float*)d_in[1];
  const float* pn_w1 = (const float*)d_in[2];
  const float* pn_b1 = (const float*)d_in[3];
  const float* pn_g1 = (const float*)d_in[4];
  const float* pn_be1 = (const float*)d_in[5];
  const float* pn_w2 = (const float*)d_in[6];
  const float* pn_b2 = (const float*)d_in[7];
  const float* pn_g2 = (const float*)d_in[8];
  const float* pn_be2 = (const float*)d_in[9];
  const float* pn_w3 = (const float*)d_in[10];
  const float* pn_b3 = (const float*)d_in[11];
  const float* pn_g3 = (const float*)d_in[12];
  const float* pn_be3 = (const float*)d_in[13];
  const float* rp_w1 = (const float*)d_in[14];
  const float* rp_b1 = (const float*)d_in[15];
  const float* rp_g1 = (const float*)d_in[16];
  const float* rp_be1 = (const float*)d_in[17];
  const float* rp_w2 = (const float*)d_in[18];
  const float* rp_b2 = (const float*)d_in[19];
  const float* rp_g2 = (const float*)d_in[20];
  const float* rp_be2 = (const float*)d_in[21];

  float* ws = (float*)d_ws;
  float* out1 = ws;                        // 524288 f (reused: W2f+bias2p)
  float* out2 = out1 + 524288;             // 1048576 f
  float* maxiou = out2 + 1048576;          // 40960
  int* maxind = (int*)(maxiou + 40960);    // 40960
  int* selpts = maxind + 40960;            // 65536
  int* rank = selpts + 65536;              // 40960
  float* aff1 = (float*)(rank + 40960);    // 128
  float* aff2 = aff1 + 128;                // 256
  float* aff3 = aff2 + 256;                // 512
  float* aff4 = aff3 + 512;                // 1024
  float* aff5 = aff4 + 1024;               // 2048
  float* psum4 = aff5 + 2048;              // 524288
  float* psq4 = psum4 + 524288;            // 524288
  unsigned short* W1f = (unsigned short*)(psq4 + 524288);  // 147456 sh = 73728 f
  float* pff_f = (float*)(W1f) + 73728;    // pff: 9437184 f
  unsigned short* pff = (unsigned short*)pff_f;
  float* g1x_f = pff_f + 9437184;          // g1x: 16777216 f
  unsigned short* g1x = (unsigned short*)g1x_f;
  float* out3T = g1x_f;                    // overlaps g1x head (dead later)
  float* iou10 = g1x_f + 2097152;          // 409600 f, overlaps g1x (dead later)
  float* maxb = pff_f;                     // overlaps pff (dead after rp1)
  float* minb = maxb + 1048576;
  float* psum5 = minb + 1048576;
  float* psq5 = psum5 + 1048576;
  unsigned short* W2f = (unsigned short*)out1;
  float* bias2p = out1 + 262144;

  float* o_feats = (float*)d_out;
  float* o_lbl = o_feats + 1048576;
  float* o_iou = o_lbl + 1024;
  float* o_box = o_iou + 1024;
  float* o_gt = o_box + 7168;
  float* o_idx = o_gt + 90;

  init_kernel<<<160, 256, 0, stream>>>(gt, o_gt, rank);
  conv_pn<4, 64, false, false, false><<<dim3(16, 1, 8), 256, 0, stream>>>(points, pn_w1, pn_b1, nullptr, out1);
  bn_stats<<<64, 256, 0, stream>>>(out1, pn_g1, pn_be1, aff1, 64);
  conv_pn<64, 128, true, true, false><<<dim3(16, 2, 8), 256, 0, stream>>>(out1, pn_w2, pn_b2, aff1, out2);
  bn_stats<<<128, 256, 0, stream>>>(out2, pn_g2, pn_be2, aff2, 128);
  conv_pn<128, 256, true, true, true><<<dim3(16, 4, 8), 256, 0, stream>>>(out2, pn_w3, pn_b3, aff2, out3T);
  bn_stats_t<<<256, 256, 0, stream>>>(out3T, pn_g3, pn_be3, aff3);
  iou_kernel<<<dim3(20, 8, 10), 256, 0, stream>>>(points, gt, iou10);
  iou_reduce<<<dim3(20, 8), 256, 0, stream>>>(iou10, maxiou, maxind);
  select_rank<<<dim3(20, 8, 8), 256, 0, stream>>>(maxiou, rank);
  select_write<<<dim3(20, 8), 256, 0, stream>>>(rank, maxiou, maxind, points, o_lbl, o_iou, o_box, o_idx);
  pool_kernel<<<256, 256, 0, stream>>>(points, o_box, selpts);
  gather_pf<<<1024, 256, 0, stream>>>(out3T, points, selpts, o_box, aff3, pff);
  prep_w1<<<512, 64, 0, stream>>>(rp_w1, W1f);
  rp1_mfma<<<2048, 256, 0, stream>>>(W1f, pff, rp_b1, g1x, psum4, psq4);
  bn_aff_part<<<512, 64, 0, stream>>>(psum4, psq4, rp_g1, rp_be1, aff4, 512);
  prep_w2<<<1024, 64, 0, stream>>>(rp_w2, rp_b2, aff4, W2f, bias2p);
  rp2_mfma<<<2048, 256, 0, stream>>>(W2f, g1x, bias2p, maxb, minb, psum5, psq5);
  bn_aff_part<<<1024, 64, 0, stream>>>(psum5, psq5, rp_g2, rp_be2, aff5, 1024);
  feats_kernel<<<4096, 256, 0, stream>>>(maxb, minb, aff5, o_feats);
}

// Round 14
// 461.935 us; speedup vs baseline: 1.0851x; 1.0851x over previous
//
#include <hip/hip_runtime.h>
#include <hip/hip_bf16.h>
#include <float.h>
#include <math.h>

// ---------------------------------------------------------------------------
// B=8, NCH=4, NPTS=1024, NGT=10, NANCH=5120, M=128, NPOOL=64, EXT=0.2
// NEW_CENTERS: (0,0,1),(0,0,-1),(2.5,0,-1),(2.5,0,1),(2.5,0,0)
// ---------------------------------------------------------------------------

typedef __attribute__((ext_vector_type(8))) short short8;
typedef __attribute__((ext_vector_type(4))) float f32x4;

#define FMA16()                                                                 \
  do {                                                                          \
    float4 av = *(const float4*)&sWT[cc][to * 4];                               \
    float4 bv = *(const float4*)&sB[cc][tk * 4];                                \
    acc[0][0] = fmaf(av.x, bv.x, acc[0][0]);                                    \
    acc[0][1] = fmaf(av.x, bv.y, acc[0][1]);                                    \
    acc[0][2] = fmaf(av.x, bv.z, acc[0][2]);                                    \
    acc[0][3] = fmaf(av.x, bv.w, acc[0][3]);                                    \
    acc[1][0] = fmaf(av.y, bv.x, acc[1][0]);                                    \
    acc[1][1] = fmaf(av.y, bv.y, acc[1][1]);                                    \
    acc[1][2] = fmaf(av.y, bv.z, acc[1][2]);                                    \
    acc[1][3] = fmaf(av.y, bv.w, acc[1][3]);                                    \
    acc[2][0] = fmaf(av.z, bv.x, acc[2][0]);                                    \
    acc[2][1] = fmaf(av.z, bv.y, acc[2][1]);                                    \
    acc[2][2] = fmaf(av.z, bv.z, acc[2][2]);                                    \
    acc[2][3] = fmaf(av.z, bv.w, acc[2][3]);                                    \
    acc[3][0] = fmaf(av.w, bv.x, acc[3][0]);                                    \
    acc[3][1] = fmaf(av.w, bv.y, acc[3][1]);                                    \
    acc[3][2] = fmaf(av.w, bv.z, acc[3][2]);                                    \
    acc[3][3] = fmaf(av.w, bv.w, acc[3][3]);                                    \
  } while (0)

// ---------------- init: copy gt tail + zero rank array ----------------------
__global__ void init_kernel(const float* __restrict__ gt, float* __restrict__ o_gt,
                            int* __restrict__ rank) {
  int t = blockIdx.x * 256 + threadIdx.x;
  if (t < 40960) rank[t] = 0;
  if (t < 90) o_gt[t] = gt[630 + t];
}

// ---------------- pointnet 1x1 conv (+optional input affine/relu) -----------
template <int C, int O, bool AFF, bool RELU, bool TRANS>
__global__ __launch_bounds__(256) void conv_pn(const float* __restrict__ in,
                                               const float* __restrict__ w,
                                               const float* __restrict__ bias,
                                               const float* __restrict__ aff,
                                               float* __restrict__ out) {
  __shared__ __align__(16) float sB[64][68];
  __shared__ __align__(16) float sWT[64][68];
  const int i0 = blockIdx.x * 64;
  const int o0 = blockIdx.y * 64;
  const int b = blockIdx.z;
  const int tid = threadIdx.x;
  const int tk = tid & 15, to = tid >> 4;
  float acc[4][4] = {};
  for (int c0 = 0; c0 < C; c0 += 64) {
    const int cs = (C - c0 < 64) ? (C - c0) : 64;
    for (int idx = tid; idx < 4096; idx += 256) {
      int ii = idx & 63, cc = idx >> 6;
      float v = 0.f;
      if (cc < cs) {
        int c = c0 + cc;
        v = in[(b * C + c) * 1024 + i0 + ii];
        if (AFF) v = fmaf(v, aff[c], aff[C + c]);
        if (RELU) v = fmaxf(v, 0.f);
      }
      sB[cc][ii] = v;
    }
    for (int idx = tid; idx < 4096; idx += 256) {
      int cc = idx & 63, oo = idx >> 6;
      sWT[cc][oo] = (cc < cs) ? w[(o0 + oo) * C + c0 + cc] : 0.f;
    }
    __syncthreads();
    for (int cc = 0; cc < cs; ++cc) { FMA16(); }
    __syncthreads();
  }
  if (TRANS) {
    float b0 = bias[o0 + to * 4], b1 = bias[o0 + to * 4 + 1];
    float b2 = bias[o0 + to * 4 + 2], b3 = bias[o0 + to * 4 + 3];
#pragma unroll
    for (int jj = 0; jj < 4; ++jj) {
      float4 v = make_float4(acc[0][jj] + b0, acc[1][jj] + b1, acc[2][jj] + b2, acc[3][jj] + b3);
      *(float4*)&out[((size_t)(b * 1024) + i0 + tk * 4 + jj) * O + o0 + to * 4] = v;
    }
  } else {
    for (int j = 0; j < 4; ++j) {
      int o = o0 + to * 4 + j;
      float bs = bias[o];
      float4 v = make_float4(acc[j][0] + bs, acc[j][1] + bs, acc[j][2] + bs, acc[j][3] + bs);
      *(float4*)&out[(b * O + o) * 1024 + i0 + tk * 4] = v;
    }
  }
}

// ---------------- BN stats over (B=8, N=1024) per channel -> affine ---------
__global__ __launch_bounds__(256) void bn_stats(const float* __restrict__ x,
                                                const float* __restrict__ g,
                                                const float* __restrict__ be,
                                                float* __restrict__ aff, int C) {
#pragma clang fp contract(off)
  int c = blockIdx.x;
  int tid = threadIdx.x;
  float s = 0.f, q = 0.f;
  for (int idx = tid; idx < 8192; idx += 256) {
    int b = idx >> 10, i = idx & 1023;
    float v = x[(b * C + c) * 1024 + i];
    s += v;
    q += v * v;
  }
  for (int m = 1; m < 64; m <<= 1) {
    s += __shfl_xor(s, m);
    q += __shfl_xor(q, m);
  }
  __shared__ float as_[4], aq_[4];
  int wv = tid >> 6;
  if ((tid & 63) == 0) { as_[wv] = s; aq_[wv] = q; }
  __syncthreads();
  if (tid == 0) {
    s = as_[0] + as_[1] + as_[2] + as_[3];
    q = aq_[0] + aq_[1] + aq_[2] + aq_[3];
    float m_ = s * (1.f / 8192.f);
    float var = q * (1.f / 8192.f) - m_ * m_;
    float A = g[c] / sqrtf(var + 1e-5f);
    aff[c] = A;
    aff[C + c] = be[c] - m_ * A;
  }
}

// ---------------- BN stats for transposed layout [8192][256] ----------------
__global__ __launch_bounds__(256) void bn_stats_t(const float* __restrict__ x,
                                                  const float* __restrict__ g,
                                                  const float* __restrict__ be,
                                                  float* __restrict__ aff) {
#pragma clang fp contract(off)
  int c = blockIdx.x;
  int tid = threadIdx.x;
  float s = 0.f, q = 0.f;
  for (int idx = tid; idx < 8192; idx += 256) {
    float v = x[(size_t)idx * 256 + c];
    s += v;
    q += v * v;
  }
  for (int m = 1; m < 64; m <<= 1) {
    s += __shfl_xor(s, m);
    q += __shfl_xor(q, m);
  }
  __shared__ float as_[4], aq_[4];
  int wv = tid >> 6;
  if ((tid & 63) == 0) { as_[wv] = s; aq_[wv] = q; }
  __syncthreads();
  if (tid == 0) {
    s = as_[0] + as_[1] + as_[2] + as_[3];
    q = aq_[0] + aq_[1] + aq_[2] + aq_[3];
    float m_ = s * (1.f / 8192.f);
    float var = q * (1.f / 8192.f) - m_ * m_;
    float A = g[c] / sqrtf(var + 1e-5f);
    aff[c] = A;
    aff[256 + c] = be[c] - m_ * A;
  }
}

// ---------------- BEV IoU (no fp contraction: match XLA elementwise) --------
__device__ float bev_iou_ga(const float* gx, const float* gz, float garea, float ax, float az) {
#pragma clang fp contract(off)
  float px[8], pz[8], ox[8], oz[8];
#pragma unroll
  for (int i = 0; i < 4; ++i) {
    px[i] = gx[i];
    pz[i] = gz[i];
    px[i + 4] = 0.f;
    pz[i + 4] = 0.f;
  }
  int count = 4;
  float kx[4], kz[4];
  kx[0] = ax + 1.f;  kz[0] = az + 2.5f;
  kx[1] = ax - 1.f;  kz[1] = az + 2.5f;
  kx[2] = ax - 1.f;  kz[2] = az - 2.5f;
  kx[3] = ax + 1.f;  kz[3] = az - 2.5f;
#pragma unroll
  for (int e = 0; e < 4; ++e) {
    float e1x = kx[e], e1z = kz[e];
    float e2x = kx[(e + 1) & 3], e2z = kz[(e + 1) & 3];
    float ex = e2x - e1x, ez = e2z - e1z;
    int cnt = count > 1 ? count : 1;
    int lim = count < 8 ? count : 8;
    int p = 0;
    for (int idx = 0; idx < lim; ++idx) {
      int ni = (idx + 1) % cnt;
      if (ni > 7) ni = 7;
      float cx = px[idx], cz = pz[idx];
      float nx = px[ni], nz = pz[ni];
      float dc = ex * (cz - e1z) - ez * (cx - e1x);
      float dn = ex * (nz - e1z) - ez * (nx - e1x);
      bool ic = dc >= 0.f, in_ = dn >= 0.f;
      if (ic) {
        if (p < 8) { ox[p] = cx; oz[p] = cz; }
        ++p;
      }
      if (ic != in_) {
        float den = dc - dn;
        float t = dc / (fabsf(den) < 1e-9f ? 1e-9f : den);
        if (p < 8) { ox[p] = cx + t * (nx - cx); oz[p] = cz + t * (nz - cz); }
        ++p;
      }
    }
    count = p;
    int cp = p < 8 ? p : 8;
#pragma unroll
    for (int i = 0; i < 8; ++i) {
      px[i] = (i < cp) ? ox[i] : 0.f;
      pz[i] = (i < cp) ? oz[i] : 0.f;
    }
  }
  int cnt = count > 1 ? count : 1;
  int lim = count < 8 ? count : 8;
  float ssum = 0.f;
  for (int idx = 0; idx < lim; ++idx) {
    int ni = (idx + 1) % cnt;
    if (ni > 7) ni = 7;
    ssum += px[idx] * pz[ni] - px[ni] * pz[idx];
  }
  float inter = 0.5f * fabsf(ssum);
  return inter / fmaxf(garea + 10.f - inter, 1e-8f);
}

// ---------------- iou: one (anchor, gt) per thread, grid (20,8,10) ----------
__global__ __launch_bounds__(256) void iou_kernel(const float* __restrict__ points,
                                                  const float* __restrict__ gt,
                                                  float* __restrict__ iou10) {
#pragma clang fp contract(off)
  int b = blockIdx.y, g = blockIdx.z;
  int a = blockIdx.x * 256 + threadIdx.x;
  const float* L = gt + b * 90 + g * 9;
  float gxx = L[3], gzz = L[5], gw = L[0], gl = L[2], gth = L[6];
  float c = cosf(gth), s = sinf(gth);
  const float sx[4] = {0.5f, -0.5f, -0.5f, 0.5f};
  const float sz[4] = {0.5f, 0.5f, -0.5f, -0.5f};
  float gcx[4], gcz[4];
#pragma unroll
  for (int k = 0; k < 4; ++k) {
    float lx = sx[k] * gw, lz = sz[k] * gl;
    gcx[k] = gxx + lx * c - lz * s;
    gcz[k] = gzz + lx * s + lz * c;
  }
  float garea = gw * gl;
  int pt = a / 5, j = a % 5;
  const float CX[5] = {0.f, 0.f, 2.5f, 2.5f, 2.5f};
  const float CZ[5] = {1.f, -1.f, -1.f, 1.f, 0.f};
  const float* P = points + b * 4096;
  float ax = P[pt] - CX[j];
  float az = P[2048 + pt] - CZ[j];
  iou10[(size_t)(b * 10 + g) * 5120 + a] = bev_iou_ga(gcx, gcz, garea, ax, az);
}

// ---------------- argmax over g (strict >, first max wins) ------------------
__global__ __launch_bounds__(256) void iou_reduce(const float* __restrict__ iou10,
                                                  float* __restrict__ maxiou,
                                                  int* __restrict__ maxind) {
  int b = blockIdx.y;
  int a = blockIdx.x * 256 + threadIdx.x;
  float best = -1.f;
  int bi = 0;
  for (int g = 0; g < 10; ++g) {
    float v = iou10[(size_t)(b * 10 + g) * 5120 + a];
    if (v > best) { best = v; bi = g; }
  }
  maxiou[b * 5120 + a] = best;
  maxind[b * 5120 + a] = bi;
}

// ---------------- rank: partial counts over j-chunks (order-independent) ----
__global__ __launch_bounds__(256) void select_rank(const float* __restrict__ maxiou,
                                                   int* __restrict__ rank) {
  __shared__ __align__(16) float vals[640];
  int b = blockIdx.y, chunk = blockIdx.z, tid = threadIdx.x;
  int jb0 = chunk * 640;
  for (int i = tid; i < 640; i += 256) vals[i] = maxiou[b * 5120 + jb0 + i];
  int a = blockIdx.x * 256 + tid;
  float av = maxiou[b * 5120 + a];
  __syncthreads();
  int rk = 0;
#pragma unroll 4
  for (int j4 = 0; j4 < 160; ++j4) {
    float4 v = *(const float4*)&vals[j4 * 4];
    int jb = jb0 + j4 * 4;
    rk += (v.x < av) || (v.x == av && jb < a);
    rk += (v.y < av) || (v.y == av && jb + 1 < a);
    rk += (v.z < av) || (v.z == av && jb + 2 < a);
    rk += (v.w < av) || (v.w == av && jb + 3 < a);
  }
  atomicAdd(&rank[b * 5120 + a], rk);
}

// ---------------- write selected rows from final ranks ----------------------
__global__ __launch_bounds__(256) void select_write(const int* __restrict__ rank,
                                                    const float* __restrict__ maxiou,
                                                    const int* __restrict__ maxind,
                                                    const float* __restrict__ points,
                                                    float* __restrict__ o_lbl,
                                                    float* __restrict__ o_iou,
                                                    float* __restrict__ o_box,
                                                    float* __restrict__ o_idx) {
#pragma clang fp contract(off)
  int b = blockIdx.y, tid = threadIdx.x;
  int a = blockIdx.x * 256 + tid;
  int rk = rank[b * 5120 + a];
  int slot = -1;
  if (rk < 64) slot = rk;
  else if (rk >= 5056) slot = rk - 4992;  // 64 + (rk - 5056)
  if (slot >= 0) {
    const float CX[5] = {0.f, 0.f, 2.5f, 2.5f, 2.5f};
    const float CZ[5] = {1.f, -1.f, -1.f, 1.f, 0.f};
    int base = b * 128 + slot;
    float av = maxiou[b * 5120 + a];
    o_iou[base] = av;
    o_lbl[base] = av > 0.5f ? 1.f : 0.f;
    o_idx[base] = (float)maxind[b * 5120 + a];
    int pt = a / 5, j = a % 5;
    const float* P = points + b * 4096;
    float* bx = o_box + base * 7;
    bx[0] = P[pt] - CX[j];
    bx[1] = P[1024 + pt];
    bx[2] = P[2048 + pt] - CZ[j];
    bx[3] = 2.f;
    bx[4] = 2.f;
    bx[5] = 5.f;
    bx[6] = 0.f;
  }
}

// ---------------- pooling: ballot-based, exact point-index order ------------
__global__ __launch_bounds__(256) void pool_kernel(const float* __restrict__ points,
                                                   const float* __restrict__ selboxes,
                                                   int* __restrict__ selpts) {
#pragma clang fp contract(off)
  int box = blockIdx.x * 4 + (threadIdx.x >> 6);
  int lane = threadIdx.x & 63;
  int b = box >> 7;
  const float* bx = selboxes + box * 7;
  float b0 = bx[0], b1 = bx[1], b2 = bx[2], b3 = bx[3], b4 = bx[4], b5 = bx[5];
  float limx = b4 * 0.5f + 0.2f, limz = b5 * 0.5f + 0.2f;
  float ylo = b1 - b3 - 0.2f, yhi = b1 + 0.2f;
  const float* P = points + b * 4096;
  unsigned long long m[16];
  int total_in = 0;
#pragma unroll
  for (int r = 0; r < 16; ++r) {
    int pt = r * 64 + lane;
    float dx = P[pt] - b0;
    float py = P[1024 + pt];
    float dz = P[2048 + pt] - b2;
    bool ins = (fabsf(dx) < limx) && (fabsf(dz) < limz) && (py > ylo) && (py < yhi);
    m[r] = __ballot(ins);
    total_in += __popcll(m[r]);
  }
  unsigned long long lowmask = (1ull << lane) - 1;
  int cum = 0;
#pragma unroll
  for (int r = 0; r < 16; ++r) {
    int pt = r * 64 + lane;
    int inbefore = cum + __popcll(m[r] & lowmask);
    bool ins = (m[r] >> lane) & 1;
    int slot = ins ? inbefore : total_in + (pt - inbefore);
    if (slot < 64) selpts[box * 64 + slot] = pt | (ins ? 0x10000 : 0);
    cum += __popcll(m[r]);
  }
}

// ---------------- gather pooled features -> bf16 B-fragment order -----------
__global__ __launch_bounds__(256) void gather_pf(const float* __restrict__ out3T,
                                                 const float* __restrict__ points,
                                                 const int* __restrict__ selpts,
                                                 const float* __restrict__ selboxes,
                                                 const float* __restrict__ aff3,
                                                 unsigned short* __restrict__ pff) {
  __shared__ int sSel[64];
  __shared__ float sCen[3];
  __shared__ float sA3[256], sB3[256];
  const int bm = blockIdx.x;
  const int b = bm >> 7;
  const int tid = threadIdx.x;
  if (tid < 64) sSel[tid] = selpts[bm * 64 + tid];
  if (tid >= 64 && tid < 67) sCen[tid - 64] = selboxes[bm * 7 + (tid - 64)];
  sA3[tid] = aff3[tid];
  sB3[tid] = aff3[256 + tid];
  __syncthreads();
  const int pool = tid >> 2, part = tid & 3;
  const int ni = pool >> 4, nib = pool & 15;
  const int sv = sSel[pool];
  const int pt = sv & 0xFFFF;
  const bool valid = (sv >> 16) != 0;
  const float* row = out3T + ((size_t)(b << 10) + pt) * 256;
#pragma unroll
  for (int ks = 0; ks < 8; ++ks) {
    int c0 = ks * 32 + part * 8;
    float4 x0 = *(const float4*)&row[c0];
    float4 x1 = *(const float4*)&row[c0 + 4];
    float v[8] = {x0.x, x0.y, x0.z, x0.w, x1.x, x1.y, x1.z, x1.w};
    union { __hip_bfloat16 h[8]; uint4 u; } pk;
#pragma unroll
    for (int e = 0; e < 8; ++e) {
      float vv = valid ? fmaf(v[e], sA3[c0 + e], sB3[c0 + e]) : 0.f;
      pk.h[e] = __float2bfloat16(vv);
    }
    *(uint4*)&pff[((size_t)((bm * 9 + ks) * 4 + ni) * 64 + part * 16 + nib) * 8] = pk.u;
  }
  union { __hip_bfloat16 h[8]; uint4 u; } pk;
#pragma unroll
  for (int e = 0; e < 8; ++e) pk.h[e] = __float2bfloat16(0.f);
  if (part == 0) {
#pragma unroll
    for (int d = 0; d < 3; ++d) {
      float pv = valid ? points[(b * 4 + d) * 1024 + pt] : 0.f;
      pk.h[d] = __float2bfloat16(pv - sCen[d]);
    }
  }
  *(uint4*)&pff[((size_t)((bm * 9 + 8) * 4 + ni) * 64 + part * 16 + nib) * 8] = pk.u;
}

// ---------------- prep W1: A-fragment order [tile32][ks9][lane64][8] --------
__global__ __launch_bounds__(64) void prep_w1(const float* __restrict__ w1,
                                              unsigned short* __restrict__ W1f) {
  int o = blockIdx.x;
  int lp = threadIdx.x;
  if (lp >= 36) return;
  int ks = lp >> 2, quad = lp & 3;
  int tile = o >> 4;
  union { __hip_bfloat16 h[8]; uint4 u; } pk;
#pragma unroll
  for (int j = 0; j < 8; ++j) {
    int c = ks * 32 + quad * 8 + j;
    float v = (c < 259) ? w1[o * 259 + c] : 0.f;
    pk.h[j] = __float2bfloat16(v);
  }
  *(uint4*)&W1f[((size_t)(tile * 9 + ks) * 64 + quad * 16 + (o & 15)) * 8] = pk.u;
}

// ---------------- rp1: LDS-free register MFMA + ot-fastest XCD swizzle ------
__global__ __launch_bounds__(256) void rp1_mfma(const unsigned short* __restrict__ W1f,
                                                const unsigned short* __restrict__ pff,
                                                const float* __restrict__ bias1,
                                                unsigned short* __restrict__ g1x,
                                                float* __restrict__ psum4,
                                                float* __restrict__ psq4) {
  const int tid = threadIdx.x;
  const int lane = tid & 63, w = tid >> 6;
  const int quad = lane >> 4, nib = lane & 15;
  const int l = blockIdx.x;            // 2048 blocks
  const int xcd = l & 7;
  const int j = l >> 3;                // 0..255
  const int ot = j & 1;
  const int bm = xcd * 128 + (j >> 1);
  const unsigned short* Aw = &W1f[((size_t)(ot * 4 + w) * 4 * 9 * 64 + lane) * 8];
  const unsigned short* Bw = &pff[((size_t)(bm * 9) * 4 * 64 + lane) * 8];
  f32x4 acc[4][4] = {};
#pragma unroll
  for (int ks = 0; ks < 9; ++ks) {
    short8 af[4], bf[4];
#pragma unroll
    for (int mi = 0; mi < 4; ++mi)
      af[mi] = *(const short8*)&Aw[(size_t)(mi * 9 + ks) * 512];
#pragma unroll
    for (int ni = 0; ni < 4; ++ni)
      bf[ni] = *(const short8*)&Bw[(size_t)(ks * 4 + ni) * 512];
#pragma unroll
    for (int mi = 0; mi < 4; ++mi)
#pragma unroll
      for (int ni = 0; ni < 4; ++ni)
        acc[mi][ni] = __builtin_amdgcn_mfma_f32_16x16x32_bf16(af[mi], bf[ni], acc[mi][ni], 0, 0, 0);
  }
  const int cbase = ot * 256 + w * 64;
#pragma unroll
  for (int mi = 0; mi < 4; ++mi) {
    float bv[4];
#pragma unroll
    for (int r = 0; r < 4; ++r) bv[r] = bias1[cbase + mi * 16 + quad * 4 + r];
    float s[4] = {0.f, 0.f, 0.f, 0.f}, q[4] = {0.f, 0.f, 0.f, 0.f};
    const int kgbase = (cbase + mi * 16) >> 3;
#pragma unroll
    for (int ni = 0; ni < 4; ++ni) {
      union { __hip_bfloat16 h[4]; unsigned int u[2]; } pk;
#pragma unroll
      for (int r = 0; r < 4; ++r) {
        float v = acc[mi][ni][r] + bv[r];
        pk.h[r] = __float2bfloat16(v);
        s[r] += v;
        q[r] += v * v;
      }
      unsigned int p0 = (unsigned int)__shfl_xor((int)pk.u[0], 16);
      unsigned int p1 = (unsigned int)__shfl_xor((int)pk.u[1], 16);
      if ((quad & 1) == 0) {
        uint4 g = make_uint4(pk.u[0], pk.u[1], p0, p1);
        int kg = kgbase + (quad >> 1);
        *(uint4*)&g1x[((size_t)(bm * 64 + kg) * 64 + ni * 16 + nib) * 8] = g;
      }
    }
#pragma unroll
    for (int r = 0; r < 4; ++r) {
      float ss = s[r], qq = q[r];
#pragma unroll
      for (int msk = 1; msk < 16; msk <<= 1) {
        ss += __shfl_xor(ss, msk);
        qq += __shfl_xor(qq, msk);
      }
      if (nib == 0) {
        int o = cbase + mi * 16 + quad * 4 + r;
        psum4[bm * 512 + o] = ss;
        psq4[bm * 512 + o] = qq;
      }
    }
  }
}

// ---------------- BN affine from per-bm partials (C=512 or 1024) -----------
__global__ __launch_bounds__(64) void bn_aff_part(const float* __restrict__ psum,
                                                  const float* __restrict__ psq,
                                                  const float* __restrict__ g,
                                                  const float* __restrict__ be,
                                                  float* __restrict__ aff, int C) {
#pragma clang fp contract(off)
  int o = blockIdx.x;
  int lane = threadIdx.x;
  float s = 0.f, q = 0.f;
  for (int i = 0; i < 16; ++i) {
    int bm = i * 64 + lane;
    s += psum[(size_t)bm * C + o];
    q += psq[(size_t)bm * C + o];
  }
  for (int m = 1; m < 64; m <<= 1) {
    s += __shfl_xor(s, m);
    q += __shfl_xor(q, m);
  }
  if (lane == 0) {
    float m_ = s * (1.f / 65536.f);
    float var = q * (1.f / 65536.f) - m_ * m_;
    float A = g[o] / sqrtf(var + 1e-5f);
    aff[o] = A;
    aff[C + o] = be[o] - m_ * A;
  }
}

// ---------------- prep W2: fold BN4, A-fragment order [tile64][ks16][lane][8]
__global__ __launch_bounds__(64) void prep_w2(const float* __restrict__ w2,
                                              const float* __restrict__ b2,
                                              const float* __restrict__ aff4,
                                              unsigned short* __restrict__ W2f,
                                              float* __restrict__ bias2p) {
  int o = blockIdx.x;
  int lp = threadIdx.x;
  int ks = lp >> 2, quad = lp & 3;
  int tile = o >> 4;
  float accb = 0.f;
  union { __hip_bfloat16 h[8]; uint4 u; } pk;
#pragma unroll
  for (int j = 0; j < 8; ++j) {
    int c = ks * 32 + quad * 8 + j;
    float wv = w2[o * 512 + c];
    pk.h[j] = __float2bfloat16(wv * aff4[c]);
    accb += wv * aff4[512 + c];
  }
  *(uint4*)&W2f[((size_t)(tile * 16 + ks) * 64 + quad * 16 + (o & 15)) * 8] = pk.u;
  for (int m = 1; m < 64; m <<= 1) accb += __shfl_xor(accb, m);
  if (lp == 0) bias2p[o] = b2[o] + accb;
}

// ---------------- rp2: LDS-free register MFMA + ot-fastest XCD swizzle ------
// (round-10 form: best measured — VGPR 72, ~30% occupancy, 116 us)
__global__ __launch_bounds__(256) void rp2_mfma(const unsigned short* __restrict__ W2f,
                                                const unsigned short* __restrict__ g1x,
                                                const float* __restrict__ bias2p,
                                                float* __restrict__ maxb,
                                                float* __restrict__ minb,
                                                float* __restrict__ psum,
                                                float* __restrict__ psq) {
  const int tid = threadIdx.x;
  const int lane = tid & 63, w = tid >> 6;
  const int quad = lane >> 4, nib = lane & 15;
  const int l = blockIdx.x;            // 4096 blocks
  const int xcd = l & 7;
  const int j = l >> 3;                // 0..511
  const int ot = j & 3;
  const int bm = xcd * 128 + (j >> 2);
  const unsigned short* Aw = &W2f[((size_t)(ot * 4 + w) * 4 * 16 * 64 + lane) * 8];
  // base short-offset = (bm*4096 + quad*64 + nib)*8; + ks*2048 + ni*128
  const unsigned short* Bw = &g1x[((size_t)bm * 4096 + quad * 64 + nib) * 8];
  f32x4 acc[4][4] = {};
#pragma unroll
  for (int ks = 0; ks < 16; ++ks) {
    short8 af[4], bf[4];
#pragma unroll
    for (int mi = 0; mi < 4; ++mi)
      af[mi] = *(const short8*)&Aw[(size_t)(mi * 16 + ks) * 512];
#pragma unroll
    for (int ni = 0; ni < 4; ++ni)
      bf[ni] = *(const short8*)&Bw[(size_t)ks * 2048 + (size_t)ni * 128];
#pragma unroll
    for (int mi = 0; mi < 4; ++mi)
#pragma unroll
      for (int ni = 0; ni < 4; ++ni)
        acc[mi][ni] = __builtin_amdgcn_mfma_f32_16x16x32_bf16(af[mi], bf[ni], acc[mi][ni], 0, 0, 0);
  }
  const int obase = ot * 256 + w * 64;
#pragma unroll
  for (int mi = 0; mi < 4; ++mi) {
#pragma unroll
    for (int r = 0; r < 4; ++r) {
      int o = obase + mi * 16 + quad * 4 + r;
      float bs = bias2p[o];
      float v0 = acc[mi][0][r] + bs;
      float v1 = acc[mi][1][r] + bs;
      float v2 = acc[mi][2][r] + bs;
      float v3 = acc[mi][3][r] + bs;
      float mx = fmaxf(fmaxf(v0, v1), fmaxf(v2, v3));
      float mn = fminf(fminf(v0, v1), fminf(v2, v3));
      float s = v0 + v1 + v2 + v3;
      float q = v0 * v0 + v1 * v1 + v2 * v2 + v3 * v3;
#pragma unroll
      for (int msk = 1; msk < 16; msk <<= 1) {
        mx = fmaxf(mx, __shfl_xor(mx, msk));
        mn = fminf(mn, __shfl_xor(mn, msk));
        s += __shfl_xor(s, msk);
        q += __shfl_xor(q, msk);
      }
      if (nib == 0) {
        maxb[bm * 1024 + o] = mx;
        minb[bm * 1024 + o] = mn;
        psum[bm * 1024 + o] = s;
        psq[bm * 1024 + o] = q;
      }
    }
  }
}

// ---------------- feats: monotone-affine max over NPOOL --------------------
__global__ void feats_kernel(const float* __restrict__ maxb, const float* __restrict__ minb,
                             const float* __restrict__ aff5, float* __restrict__ o_feats) {
#pragma clang fp contract(off)
  int i = blockIdx.x * 256 + threadIdx.x;
  int o = i & 1023;
  float A = aff5[o], Bv = aff5[1024 + o];
  float v = (A >= 0.f) ? maxb[i] : minb[i];
  o_feats[i] = v * A + Bv;
}

// ---------------------------------------------------------------------------
extern "C" void kernel_launch(void* const* d_in, const int* in_sizes, int n_in,
                              void* d_out, int out_size, void* d_ws, size_t ws_size,
                              hipStream_t stream) {
  (void)in_sizes; (void)n_in; (void)out_size; (void)ws_size;
  const float* points = (const float*)d_in[0];
  const float* gt = (const float*)d_in[1];
  const float* pn_w1 = (const float*)d_in[2];
  const float* pn_b1 = (const float*)d_in[3];
  const float* pn_g1 = (const float*)d_in[4];
  const float* pn_be1 = (const float*)d_in[5];
  const float* pn_w2 = (const float*)d_in[6];
  const float* pn_b2 = (const float*)d_in[7];
  const float* pn_g2 = (const float*)d_in[8];
  const float* pn_be2 = (const float*)d_in[9];
  const float* pn_w3 = (const float*)d_in[10];
  const float* pn_b3 = (const float*)d_in[11];
  const float* pn_g3 = (const float*)d_in[12];
  const float* pn_be3 = (const float*)d_in[13];
  const float* rp_w1 = (const float*)d_in[14];
  const float* rp_b1 = (const float*)d_in[15];
  const float* rp_g1 = (const float*)d_in[16];
  const float* rp_be1 = (const float*)d_in[17];
  const float* rp_w2 = (const float*)d_in[18];
  const float* rp_b2 = (const float*)d_in[19];
  const float* rp_g2 = (const float*)d_in[20];
  const float* rp_be2 = (const float*)d_in[21];

  float* ws = (float*)d_ws;
  float* out1 = ws;                        // 524288 f (reused: W2f+bias2p)
  float* out2 = out1 + 524288;             // 1048576 f
  float* maxiou = out2 + 1048576;          // 40960
  int* maxind = (int*)(maxiou + 40960);    // 40960
  int* selpts = maxind + 40960;            // 65536
  int* rank = selpts + 65536;              // 40960
  float* aff1 = (float*)(rank + 40960);    // 128
  float* aff2 = aff1 + 128;                // 256
  float* aff3 = aff2 + 256;                // 512
  float* aff4 = aff3 + 512;                // 1024
  float* aff5 = aff4 + 1024;               // 2048
  float* psum4 = aff5 + 2048;              // 524288
  float* psq4 = psum4 + 524288;            // 524288
  unsigned short* W1f = (unsigned short*)(psq4 + 524288);  // 147456 sh = 73728 f
  float* pff_f = (float*)(W1f) + 73728;    // pff: 9437184 f
  unsigned short* pff = (unsigned short*)pff_f;
  float* g1x_f = pff_f + 9437184;          // g1x: 16777216 f
  unsigned short* g1x = (unsigned short*)g1x_f;
  float* out3T = g1x_f;                    // overlaps g1x head (dead later)
  float* iou10 = g1x_f + 2097152;          // 409600 f, overlaps g1x (dead later)
  float* maxb = pff_f;                     // overlaps pff (dead after rp1)
  float* minb = maxb + 1048576;
  float* psum5 = minb + 1048576;
  float* psq5 = psum5 + 1048576;
  unsigned short* W2f = (unsigned short*)out1;
  float* bias2p = out1 + 262144;

  float* o_feats = (float*)d_out;
  float* o_lbl = o_feats + 1048576;
  float* o_iou = o_lbl + 1024;
  float* o_box = o_iou + 1024;
  float* o_gt = o_box + 7168;
  float* o_idx = o_gt + 90;

  init_kernel<<<160, 256, 0, stream>>>(gt, o_gt, rank);
  conv_pn<4, 64, false, false, false><<<dim3(16, 1, 8), 256, 0, stream>>>(points, pn_w1, pn_b1, nullptr, out1);
  bn_stats<<<64, 256, 0, stream>>>(out1, pn_g1, pn_be1, aff1, 64);
  conv_pn<64, 128, true, true, false><<<dim3(16, 2, 8), 256, 0, stream>>>(out1, pn_w2, pn_b2, aff1, out2);
  bn_stats<<<128, 256, 0, stream>>>(out2, pn_g2, pn_be2, aff2, 128);
  conv_pn<128, 256, true, true, true><<<dim3(16, 4, 8), 256, 0, stream>>>(out2, pn_w3, pn_b3, aff2, out3T);
  bn_stats_t<<<256, 256, 0, stream>>>(out3T, pn_g3, pn_be3, aff3);
  iou_kernel<<<dim3(20, 8, 10), 256, 0, stream>>>(points, gt, iou10);
  iou_reduce<<<dim3(20, 8), 256, 0, stream>>>(iou10, maxiou, maxind);
  select_rank<<<dim3(20, 8, 8), 256, 0, stream>>>(maxiou, rank);
  select_write<<<dim3(20, 8), 256, 0, stream>>>(rank, maxiou, maxind, points, o_lbl, o_iou, o_box, o_idx);
  pool_kernel<<<256, 256, 0, stream>>>(points, o_box, selpts);
  gather_pf<<<1024, 256, 0, stream>>>(out3T, points, selpts, o_box, aff3, pff);
  prep_w1<<<512, 64, 0, stream>>>(rp_w1, W1f);
  rp1_mfma<<<2048, 256, 0, stream>>>(W1f, pff, rp_b1, g1x, psum4, psq4);
  bn_aff_part<<<512, 64, 0, stream>>>(psum4, psq4, rp_g1, rp_be1, aff4, 512);
  prep_w2<<<1024, 64, 0, stream>>>(rp_w2, rp_b2, aff4, W2f, bias2p);
  rp2_mfma<<<4096, 256, 0, stream>>>(W2f, g1x, bias2p, maxb, minb, psum5, psq5);
  bn_aff_part<<<1024, 64, 0, stream>>>(psum5, psq5, rp_g2, rp_be2, aff5, 1024);
  feats_kernel<<<4096, 256, 0, stream>>>(maxb, minb, aff5, o_feats);
}